// Round 4
// baseline (169.545 us; speedup 1.0000x reference)
//
#include <hip/hip_runtime.h>
#include <stdint.h>

#define BATCH   65536
#define BM      128
#define NSTEP   16

typedef __bf16 bf16x8 __attribute__((ext_vector_type(8)));
typedef float  f32x16 __attribute__((ext_vector_type(16)));

__device__ __forceinline__ uint32_t f2bf1(float v) {
  uint32_t u = __float_as_uint(v);
  return (u + 0x7FFFu + ((u >> 16) & 1u)) >> 16;   // RNE bf16
}

__device__ __forceinline__ float fast_sigmoid(float x) {
  return __builtin_amdgcn_rcpf(1.0f + __expf(-x));
}
__device__ __forceinline__ float fast_tanh(float x) {
  return 1.0f - 2.0f * __builtin_amdgcn_rcpf(1.0f + __expf(2.0f * x));
}

#define WAITVM(N) asm volatile("s_waitcnt vmcnt(" #N ")" ::: "memory")

// ---------------- prep: weights -> bf16 fragment image, conflict-free order ----------------
// 16B chunk t = nb*8192 + ks*512 + kc*128 + g*32 + u5
// holds Wcat[k = ks*32 + kc*8 + i][col = g*256 + nb*32 + u5], i = 0..7
// Wcat rows 0..255 = kernel (x), 256..511 = recurrent_kernel (h).
// ds_read side: addr = kc*2048 + (g*32+ln31)*16  -> linear stride-16 = conflict-free.
__global__ __launch_bounds__(256) void prep_weights(
    const float* __restrict__ wk, const float* __restrict__ wr,
    uint4* __restrict__ img) {
  int t  = blockIdx.x * 256 + threadIdx.x;   // 0..65535
  int u5 = t & 31;
  int g  = (t >> 5) & 3;
  int kc = (t >> 7) & 3;
  int ks = (t >> 9) & 15;
  int nb = t >> 13;
  int k0  = ks * 32 + kc * 8;
  int col = g * 256 + nb * 32 + u5;
  uint32_t o[4];
#pragma unroll
  for (int p = 0; p < 4; ++p) {
    int k = k0 + p * 2;
    float s0 = (k     < 256) ? wk[(size_t)k * 1024 + col]       : wr[(size_t)(k - 256) * 1024 + col];
    float s1 = (k + 1 < 256) ? wk[(size_t)(k + 1) * 1024 + col] : wr[(size_t)(k - 255) * 1024 + col];
    o[p] = f2bf1(s0) | (f2bf1(s1) << 16);
  }
  img[t] = make_uint4(o[0], o[1], o[2], o[3]);
}

// ---------------- fused LSTM GEMM: A reg-direct, B 4-deep LDS ring, counted vmcnt ----------------
// block: 128 rows x (4 gates x 32 units), 4 waves M-stacked (wave = 32x128).
// grid 4096; XCD-chunked swizzle -> 8 nb-sharers of one A panel on one XCD (L2 dedup).
__global__ __launch_bounds__(256) void lstm_fused(
    const float* __restrict__ xp, const float* __restrict__ hp,
    const float* __restrict__ cp, const float* __restrict__ bp,
    const uint4* __restrict__ img, float* __restrict__ outp) {

  __shared__ __align__(16) char smem[32768];   // 4 x 8KB B ring buffers

  const int tid  = threadIdx.x;
  const int lane = tid & 63;
  const int wv   = tid >> 6;
  const int ln31 = lane & 31;
  const int hi32 = lane >> 5;

  // XCD-chunked bijective swizzle (4096 % 8 == 0)
  const int orig = blockIdx.x;
  const int wg   = (orig & 7) * 512 + (orig >> 3);
  const int nb   = wg & 7;
  const int rt   = wg >> 3;

  const int row = rt * BM + wv * 32 + ln31;          // this lane's A row
  const float* ar = xp + (size_t)row * 256;
  const float* hr = hp + (size_t)row * 256;
  const int koff = hi32 * 8;                          // frag k-base within 16-k half

  // B DMA: wave wv copies chunks [wv*128, wv*128+128) of each 512-chunk K-step tile
  const uint4* bsrc = img + (size_t)nb * 8192 + wv * 128 + lane;

  f32x16 acc[4];
#pragma unroll
  for (int g = 0; g < 4; ++g)
#pragma unroll
    for (int i = 0; i < 16; ++i) acc[g][i] = 0.0f;

  float4 a0[4], a1[4];   // raw fp32 A, register double-buffer (indices fold static)

  auto loadA = [&](int ks, float4* A) {
    const float* s = ((ks < 8) ? ar : hr) + (ks & 7) * 32 + koff;
    A[0] = *(const float4*)(s);
    A[1] = *(const float4*)(s + 4);
    A[2] = *(const float4*)(s + 16);
    A[3] = *(const float4*)(s + 20);
  };
  auto glds = [&](int ks, int buf) {
    const uint4* src = bsrc + (size_t)ks * 512;
    char* dst = smem + buf * 8192 + wv * 2048;       // wave-uniform base; HW adds lane*16
    __builtin_amdgcn_global_load_lds(
        (const __attribute__((address_space(1))) uint32_t*)src,
        (__attribute__((address_space(3))) uint32_t*)dst, 16, 0, 0);
    __builtin_amdgcn_global_load_lds(
        (const __attribute__((address_space(1))) uint32_t*)(src + 64),
        (__attribute__((address_space(3))) uint32_t*)(dst + 1024), 16, 0, 0);
  };
  auto mkfrag = [&](const float4* A, bf16x8* F) {
#pragma unroll
    for (int h = 0; h < 2; ++h) {
      float4 lo = A[h * 2], hi = A[h * 2 + 1];
      bf16x8 f;
      f[0] = (__bf16)lo.x; f[1] = (__bf16)lo.y; f[2] = (__bf16)lo.z; f[3] = (__bf16)lo.w;
      f[4] = (__bf16)hi.x; f[5] = (__bf16)hi.y; f[6] = (__bf16)hi.z; f[7] = (__bf16)hi.w;
      F[h] = f;
    }
  };
  auto compute = [&](int buf, const bf16x8* F) {
    const char* bb = smem + buf * 8192;
#pragma unroll
    for (int hh = 0; hh < 2; ++hh) {
      const char* bk = bb + (hh * 2 + hi32) * 2048 + ln31 * 16;
#pragma unroll
      for (int g = 0; g < 4; ++g) {
        bf16x8 bfr = *(const bf16x8*)(bk + g * 512);
        acc[g] = __builtin_amdgcn_mfma_f32_32x32x16_bf16(F[hh], bfr, acc[g], 0, 0, 0);
      }
    }
  };

  // prologue: 2 K-steps of B in flight, A(0) in flight   (8 VMEM outstanding)
  glds(0, 0);
  glds(1, 1);
  loadA(0, a0);

#pragma unroll
  for (int ks = 0; ks < NSTEP; ++ks) {
    float4* Ac = (ks & 1) ? a1 : a0;
    float4* An = (ks & 1) ? a0 : a1;
    if (ks + 2 < NSTEP) glds(ks + 2, (ks + 2) & 3);  // ring slot freed at barrier(ks-1)
    if (ks + 1 < NSTEP) loadA(ks + 1, An);
    // steady state: exactly this iter's 6 VMEM stay outstanding; A(ks), glds(ks) retired
    if (ks < NSTEP - 2)      WAITVM(6);
    else if (ks == NSTEP - 2) WAITVM(4);
    else                      WAITVM(0);
    bf16x8 F[2];
    mkfrag(Ac, F);                                   // VALU while others reach barrier
    __builtin_amdgcn_s_barrier();                    // raw: no vmcnt/lgkm drain
    compute(ks & 3, F);
  }

  // ---- epilogue: gates + cell update, in-register; nontemporal streaming ----
  const int u = nb * 32 + ln31;
  const float bi  = bp[u];
  const float bf_ = bp[256 + u];
  const float bg  = bp[512 + u];
  const float bo  = bp[768 + u];
  const int rowbase = rt * BM + wv * 32 + 4 * hi32;
  float* outh = outp;
  float* outc = outp + (size_t)BATCH * 256;
#pragma unroll
  for (int r = 0; r < 16; ++r) {
    int orow = rowbase + (r & 3) + 8 * (r >> 2);
    size_t idx = (size_t)orow * 256 + u;
    float zi = acc[0][r] + bi;
    float zf = acc[1][r] + bf_;
    float zg = acc[2][r] + bg;
    float zo = acc[3][r] + bo;
    float iv = fast_sigmoid(zi);
    float fv = fast_sigmoid(zf);
    float gv = fast_tanh(zg);
    float ov = fast_sigmoid(zo);
    float cv = __builtin_nontemporal_load(cp + idx);
    float cn = fv * cv + iv * gv;
    float hn = ov * fast_tanh(cn);
    __builtin_nontemporal_store(hn, outh + idx);
    __builtin_nontemporal_store(cn, outc + idx);
  }
}

extern "C" void kernel_launch(void* const* d_in, const int* in_sizes, int n_in,
                              void* d_out, int out_size, void* d_ws, size_t ws_size,
                              hipStream_t stream) {
  const float* x  = (const float*)d_in[0];
  const float* h  = (const float*)d_in[1];
  const float* c  = (const float*)d_in[2];
  const float* wk = (const float*)d_in[3];
  const float* wr = (const float*)d_in[4];
  const float* b  = (const float*)d_in[5];
  prep_weights<<<256, 256, 0, stream>>>(wk, wr, (uint4*)d_ws);   // 1 MB bf16 image
  lstm_fused<<<4096, 256, 0, stream>>>(x, h, c, b,
                                       (const uint4*)d_ws, (float*)d_out);
}

// Round 5
// 168.072 us; speedup vs baseline: 1.0088x; 1.0088x over previous
//
#include <hip/hip_runtime.h>
#include <stdint.h>

#define BATCH   65536
#define BM      128
#define NSTEP   16

typedef __bf16 bf16x8 __attribute__((ext_vector_type(8)));
typedef float  f32x16 __attribute__((ext_vector_type(16)));

__device__ __forceinline__ uint32_t f2bf1(float v) {
  uint32_t u = __float_as_uint(v);
  return (u + 0x7FFFu + ((u >> 16) & 1u)) >> 16;   // RNE bf16
}

__device__ __forceinline__ float fast_sigmoid(float x) {
  return __builtin_amdgcn_rcpf(1.0f + __expf(-x));
}
__device__ __forceinline__ float fast_tanh(float x) {
  return 1.0f - 2.0f * __builtin_amdgcn_rcpf(1.0f + __expf(2.0f * x));
}

#define WAITVM(N) asm volatile("s_waitcnt vmcnt(" #N ")" ::: "memory")
#define MEMF      asm volatile("" ::: "memory")

// ---------------- prep: weights -> bf16 fragment image, conflict-free order ----------------
// 16B chunk t = nb*8192 + ks*512 + kc*128 + g*32 + u5
// holds Wcat[k = ks*32 + kc*8 + i][col = g*256 + nb*32 + u5], i = 0..7
// Wcat rows 0..255 = kernel (x), 256..511 = recurrent_kernel (h).
__global__ __launch_bounds__(256) void prep_weights(
    const float* __restrict__ wk, const float* __restrict__ wr,
    uint4* __restrict__ img) {
  int t  = blockIdx.x * 256 + threadIdx.x;   // 0..65535
  int u5 = t & 31;
  int g  = (t >> 5) & 3;
  int kc = (t >> 7) & 3;
  int ks = (t >> 9) & 15;
  int nb = t >> 13;
  int k0  = ks * 32 + kc * 8;
  int col = g * 256 + nb * 32 + u5;
  uint32_t o[4];
#pragma unroll
  for (int p = 0; p < 4; ++p) {
    int k = k0 + p * 2;
    float s0 = (k     < 256) ? wk[(size_t)k * 1024 + col]       : wr[(size_t)(k - 256) * 1024 + col];
    float s1 = (k + 1 < 256) ? wk[(size_t)(k + 1) * 1024 + col] : wr[(size_t)(k - 255) * 1024 + col];
    o[p] = f2bf1(s0) | (f2bf1(s1) << 16);
  }
  img[t] = make_uint4(o[0], o[1], o[2], o[3]);
}

// ---------------- fused LSTM GEMM: 3-deep B ring prefetch, 2-iter counted-vmcnt lookahead ----------------
__global__ __launch_bounds__(256) void lstm_fused(
    const float* __restrict__ xp, const float* __restrict__ hp,
    const float* __restrict__ cp, const float* __restrict__ bp,
    const uint4* __restrict__ img, float* __restrict__ outp) {

  __shared__ __align__(16) char smem[32768];   // 4 x 8KB B ring buffers

  const int tid  = threadIdx.x;
  const int lane = tid & 63;
  const int wv   = tid >> 6;
  const int ln31 = lane & 31;
  const int hi32 = lane >> 5;

  // XCD-chunked bijective swizzle (4096 % 8 == 0): 8 nb-sharers of one A panel on one XCD.
  const int orig = blockIdx.x;
  const int wg   = (orig & 7) * 512 + (orig >> 3);
  const int nb   = wg & 7;
  const int rt   = wg >> 3;

  const int row = rt * BM + wv * 32 + ln31;
  const float* ar = xp + (size_t)row * 256;
  const float* hr = hp + (size_t)row * 256;
  const int koff = hi32 * 8;

  const uint4* bsrc = img + (size_t)nb * 8192 + wv * 128 + lane;

  f32x16 acc[4];
#pragma unroll
  for (int g = 0; g < 4; ++g)
#pragma unroll
    for (int i = 0; i < 16; ++i) acc[g][i] = 0.0f;

  float4 a[3][4];   // 3-deep A register pipeline (all indices static after unroll)

  auto loadA = [&](int ks, float4* A) {
    const float* s = ((ks < 8) ? ar : hr) + (ks & 7) * 32 + koff;
    A[0] = *(const float4*)(s);
    A[1] = *(const float4*)(s + 4);
    A[2] = *(const float4*)(s + 16);
    A[3] = *(const float4*)(s + 20);
  };
  auto glds = [&](int ks, int buf) {
    const uint4* src = bsrc + (size_t)ks * 512;
    char* dst = smem + buf * 8192 + wv * 2048;    // wave-uniform base; HW adds lane*16
    __builtin_amdgcn_global_load_lds(
        (const __attribute__((address_space(1))) uint32_t*)src,
        (__attribute__((address_space(3))) uint32_t*)dst, 16, 0, 0);
    __builtin_amdgcn_global_load_lds(
        (const __attribute__((address_space(1))) uint32_t*)(src + 64),
        (__attribute__((address_space(3))) uint32_t*)(dst + 1024), 16, 0, 0);
  };
  auto mkfrag = [&](const float4* A, bf16x8* F) {
#pragma unroll
    for (int h = 0; h < 2; ++h) {
      float4 lo = A[h * 2], hi = A[h * 2 + 1];
      bf16x8 f;
      f[0] = (__bf16)lo.x; f[1] = (__bf16)lo.y; f[2] = (__bf16)lo.z; f[3] = (__bf16)lo.w;
      f[4] = (__bf16)hi.x; f[5] = (__bf16)hi.y; f[6] = (__bf16)hi.z; f[7] = (__bf16)hi.w;
      F[h] = f;
    }
  };
  auto compute = [&](int buf, const bf16x8* F) {
    const char* bb = smem + buf * 8192;
#pragma unroll
    for (int hh = 0; hh < 2; ++hh) {
      const char* bk = bb + (hh * 2 + hi32) * 2048 + ln31 * 16;
#pragma unroll
      for (int g = 0; g < 4; ++g) {
        bf16x8 bfr = *(const bf16x8*)(bk + g * 512);
        acc[g] = __builtin_amdgcn_mfma_f32_32x32x16_bf16(F[hh], bfr, acc[g], 0, 0, 0);
      }
    }
  };

  // output/c indexing (also used for c prefetch)
  const int u = nb * 32 + ln31;
  const int rowbase = rt * BM + wv * 32 + 4 * hi32;

  // ---- prologue: pipeline fill. vmcnt issue order pinned by MEMF fences. ----
  glds(0, 0); MEMF;
  loadA(0, a[0]); MEMF;
  glds(1, 1); MEMF;
  loadA(1, a[1]); MEMF;
  glds(2, 2); MEMF;
  loadA(2, a[2]); MEMF;
  float cr[16];
#pragma unroll
  for (int r = 0; r < 16; ++r) {
    int orow = rowbase + (r & 3) + 8 * (r >> 2);
    cr[r] = __builtin_nontemporal_load(cp + (size_t)orow * 256 + u);
  }
  MEMF;
  const float bi  = bp[u];
  const float bf_ = bp[256 + u];
  const float bg  = bp[512 + u];
  const float bo  = bp[768 + u];
  MEMF;

  // ---- main loop: WAITVM leaves exactly 2 iterations (12 VMEM ops) in flight ----
#pragma unroll
  for (int ks = 0; ks < NSTEP; ++ks) {
    if (ks < 3)        WAITVM(32);   // retires A(ks),B(ks); c/bias still in flight
    else if (ks < 14)  WAITVM(12);   // retires A(ks),B(ks) exactly (c/bias done by ks=3)
    else if (ks == 14) WAITVM(6);
    else               WAITVM(0);
    __builtin_amdgcn_s_barrier();
    MEMF;                            // no LDS read hoists above the barrier
    if (ks + 3 < NSTEP) { glds(ks + 3, (ks + 3) & 3); MEMF; }
    bf16x8 F[2];
    mkfrag(a[ks % 3], F);
    if (ks + 3 < NSTEP) { loadA(ks + 3, a[ks % 3]); MEMF; }
    __builtin_amdgcn_s_setprio(1);
    compute(ks & 3, F);
    __builtin_amdgcn_s_setprio(0);
  }

  // ---- epilogue: gates + cell update; c already in registers ----
  float* outh = outp;
  float* outc = outp + (size_t)BATCH * 256;
#pragma unroll
  for (int r = 0; r < 16; ++r) {
    int orow = rowbase + (r & 3) + 8 * (r >> 2);
    size_t idx = (size_t)orow * 256 + u;
    float zi = acc[0][r] + bi;
    float zf = acc[1][r] + bf_;
    float zg = acc[2][r] + bg;
    float zo = acc[3][r] + bo;
    float iv = fast_sigmoid(zi);
    float fv = fast_sigmoid(zf);
    float gv = fast_tanh(zg);
    float ov = fast_sigmoid(zo);
    float cn = fv * cr[r] + iv * gv;
    float hn = ov * fast_tanh(cn);
    __builtin_nontemporal_store(hn, outh + idx);
    __builtin_nontemporal_store(cn, outc + idx);
  }
}

extern "C" void kernel_launch(void* const* d_in, const int* in_sizes, int n_in,
                              void* d_out, int out_size, void* d_ws, size_t ws_size,
                              hipStream_t stream) {
  const float* x  = (const float*)d_in[0];
  const float* h  = (const float*)d_in[1];
  const float* c  = (const float*)d_in[2];
  const float* wk = (const float*)d_in[3];
  const float* wr = (const float*)d_in[4];
  const float* b  = (const float*)d_in[5];
  prep_weights<<<256, 256, 0, stream>>>(wk, wr, (uint4*)d_ws);   // 1 MB bf16 image
  lstm_fused<<<4096, 256, 0, stream>>>(x, h, c, b,
                                       (const uint4*)d_ws, (float*)d_out);
}